// Round 14
// baseline (459.069 us; speedup 1.0000x reference)
//
#include <hip/hip_runtime.h>

typedef unsigned short u16;
typedef __attribute__((ext_vector_type(8))) short short8;
typedef __attribute__((ext_vector_type(4))) float f32x4;
typedef __attribute__((ext_vector_type(4))) unsigned short us4;

constexpr int B_ = 2;
constexpr int H_ = 8;
constexpr int KVH_ = 4;
constexpr int S_ = 2048;
constexpr int D_ = 256;
constexpr int HID_ = 2304;
constexpr int QKVN_ = 4096;   // 2048 q + 1024 k + 1024 v
constexpr int AON_ = 2048;    // H_*D_

__device__ __forceinline__ float b2f(u16 u) {
  union { float f; unsigned int i; } x; x.i = ((unsigned int)u) << 16; return x.f;
}
__device__ __forceinline__ u16 f2b(float f) {
  unsigned int x = __float_as_uint(f);
  unsigned int r = (x + 0x7fffu + ((x >> 16) & 1u)) >> 16;
  return (u16)r;
}
// raw v_exp_f32: computes 2^x (no ln2 conversion mul)
__device__ __forceinline__ float exp2_raw(float x) {
  float r;
  asm("v_exp_f32 %0, %1" : "=v"(r) : "v"(x));
  return r;
}
// packed f32x2 -> bf16x2 (RTNE, identical result to f2b pair)
__device__ __forceinline__ unsigned int cvt_pk_bf16(float lo, float hi) {
  unsigned int r;
  asm("v_cvt_pk_bf16_f32 %0, %1, %2" : "=v"(r) : "v"(lo), "v"(hi));
  return r;
}

// ---------------- prep: cast + 4 weight transposes, grid-strided ----
__global__ void prep_kernel(const float* __restrict__ hidden,
                            const float* __restrict__ s0, const float* __restrict__ s1,
                            const float* __restrict__ s2, const float* __restrict__ s3,
                            u16* __restrict__ hsOut,
                            u16* __restrict__ d0, u16* __restrict__ d1,
                            u16* __restrict__ d2, u16* __restrict__ d3) {
  __shared__ float tile[64][65];
  int t = threadIdx.x;
  for (int bx = blockIdx.x; bx < 12672; bx += gridDim.x) {
    if (bx < 9216) {  // cast fp32 -> bf16
      size_t i = ((size_t)bx * 256 + t) * 4;
      float4 v = *(const float4*)(hidden + i);
      unsigned int lo = (unsigned int)f2b(v.x) | ((unsigned int)f2b(v.y) << 16);
      unsigned int hi = (unsigned int)f2b(v.z) | ((unsigned int)f2b(v.w) << 16);
      uint2 o; o.x = lo; o.y = hi;
      *(uint2*)(hsOut + i) = o;
      continue;
    }
    int tt = bx - 9216;
    const float* src; u16* dst; int R, C, cx, cy;
    if (tt < 1152)              { src = s0; dst = d0; R = 2304; C = 2048; cx = tt & 31; cy = tt >> 5; }
    else if ((tt -= 1152) < 576){ src = s1; dst = d1; R = 2304; C = 1024; cx = tt & 15; cy = tt >> 4; }
    else if ((tt -= 576) < 576) { src = s2; dst = d2; R = 2304; C = 1024; cx = tt & 15; cy = tt >> 4; }
    else { tt -= 576;             src = s3; dst = d3; R = 2048; C = 2304; cx = tt % 36; cy = tt / 36; }
    int r0 = cy * 64, c0 = cx * 64;
#pragma unroll
    for (int i = 0; i < 16; ++i) {
      int e = i * 256 + t;
      int r = e >> 6, c = e & 63;
      tile[r][c] = src[(size_t)(r0 + r) * C + (c0 + c)];
    }
    __syncthreads();
#pragma unroll
    for (int i = 0; i < 8; ++i) {
      int e = i * 256 + t;
      int orow = e >> 5;
      int ocol = (e & 31) * 2;
      unsigned int w = (unsigned int)f2b(tile[ocol][orow]) |
                       ((unsigned int)f2b(tile[ocol + 1][orow]) << 16);
      *(unsigned int*)(&dst[(size_t)(c0 + orow) * R + (r0 + ocol)]) = w;
    }
    __syncthreads();  // protect shared tile before next iteration's fill
  }
}

// ---------------- 256x256-tile 8-wave 4-phase/K-tile bf16 GEMM (gemm1) ----
template <int OUTF32>
__global__ __launch_bounds__(512, 2) void gemm_bt8(
    const u16* __restrict__ A, const u16* __restrict__ B, void* __restrict__ Cp,
    int M, int N, int K) {
  __shared__ u16 lds[2][2][2][8192];  // [buf][0=A,1=B][half(128 rows)][16 KiB]
  const int tid = threadIdx.x;
  const int lane = tid & 63;
  const int wave = tid >> 6;
  const int wm = wave >> 2, wn = wave & 3;       // 2 (M) x 4 (N) waves
  const int quad = lane >> 4, l16 = lane & 15;
  const int m0 = blockIdx.y * 256, n0 = blockIdx.x * 256;
  const int nt = K >> 6;  // K-tiles of 64

  const int sub = tid >> 6;
  const int rr = (tid >> 2) & 15;
  const int cc = ((tid & 3) * 8) ^ ((rr & 8) ? 16 : 0);
  const int r_rel = (sub >> 1) * 16 + rr;   // 0..63 row within region
  const int ccol = (sub & 1) * 32 + cc;     // 0..63 k-col (pre-inverse-swizzled)
  const u16* Asrc = A + (size_t)(m0 + r_rel) * K + ccol;
  const u16* Bsrc = B + (size_t)(n0 + r_rel) * K + ccol;
  const int ldsc = tid * 8;  // u16 index of this thread's 16 B chunk in a region

  const int fr_off = l16 * 64 + (((quad * 8) ^ ((l16 & 8) ? 16 : 0)) << 1);

#define GL8(src, dst)                                                                  \
  __builtin_amdgcn_global_load_lds((const __attribute__((address_space(1))) void*)(src), \
                                   (__attribute__((address_space(3))) void*)(dst), 16, 0, 0)
#define STAGE_A(bf, kt, qp) {                                                          \
    const u16* _s = Asrc + (size_t)(kt) * 64;                                          \
    GL8(_s + (size_t)((qp) * 64) * K,       &lds[bf][0][0][(qp) * 4096 + ldsc]);       \
    GL8(_s + (size_t)(128 + (qp) * 64) * K, &lds[bf][0][1][(qp) * 4096 + ldsc]); }
#define STAGE_B(bf, kt, hf) {                                                          \
    const u16* _s = Bsrc + (size_t)(kt) * 64;                                          \
    GL8(_s + (size_t)((hf) * 128) * K,      &lds[bf][1][hf][ldsc]);                    \
    GL8(_s + (size_t)((hf) * 128 + 64) * K, &lds[bf][1][hf][4096 + ldsc]); }
#define LDA(bf, mi, kk) \
  (*(const short8*)((const char*)&lds[bf][0][wm][0] + (mi) * 2048 + (kk) * 1024 + fr_off))
#define LDB(bf, ni, kk) \
  (*(const short8*)((const char*)&lds[bf][1][wn >> 1][0] + ((wn & 1) * 4 + (ni)) * 2048 + (kk) * 1024 + fr_off))

  f32x4 acc[8][4] = {};
  short8 bfr[4][2], af[2][2];

  STAGE_B(0, 0, 0); STAGE_B(0, 0, 1); STAGE_A(0, 0, 0); STAGE_A(0, 0, 1);
  STAGE_B(1, 1, 0); STAGE_B(1, 1, 1); STAGE_A(1, 1, 0);
  asm volatile("s_waitcnt vmcnt(6)" ::: "memory");
  __builtin_amdgcn_s_barrier();

#define PHASE(q, STG, VMW)                                                             \
    _Pragma("unroll") for (int i = 0; i < 2; ++i)                                      \
      _Pragma("unroll") for (int kk = 0; kk < 2; ++kk) af[i][kk] = LDA(c, 2 * (q) + i, kk); \
    STG; VMW;                                                                          \
    __builtin_amdgcn_s_barrier();                                                      \
    asm volatile("s_waitcnt lgkmcnt(0)" ::: "memory");                                 \
    __builtin_amdgcn_sched_barrier(0);                                                 \
    __builtin_amdgcn_s_setprio(1);                                                     \
    _Pragma("unroll") for (int i = 0; i < 2; ++i)                                      \
      _Pragma("unroll") for (int ni = 0; ni < 4; ++ni)                                 \
        _Pragma("unroll") for (int kk = 0; kk < 2; ++kk)                               \
          acc[2 * (q) + i][ni] = __builtin_amdgcn_mfma_f32_16x16x32_bf16(              \
              af[i][kk], bfr[ni][kk], acc[2 * (q) + i][ni], 0, 0, 0);                  \
    __builtin_amdgcn_s_setprio(0);                                                     \
    __builtin_amdgcn_s_barrier();

  for (int T = 0; T < nt; ++T) {
    const int c = T & 1;
#pragma unroll
    for (int ni = 0; ni < 4; ++ni)
#pragma unroll
      for (int kk = 0; kk < 2; ++kk) bfr[ni][kk] = LDB(c, ni, kk);
    PHASE(0, if (T + 1 < nt) STAGE_A(c ^ 1, T + 1, 1), )
    PHASE(1, if (T + 2 < nt) STAGE_B(c, T + 2, 0), )
    PHASE(2, if (T + 2 < nt) STAGE_B(c, T + 2, 1), )
    PHASE(3, if (T + 2 < nt) STAGE_A(c, T + 2, 0),
          if (T + 2 >= nt) { asm volatile("s_waitcnt vmcnt(0)" ::: "memory"); }
          else             { asm volatile("s_waitcnt vmcnt(6)" ::: "memory"); })
  }
#undef PHASE
#undef LDA
#undef LDB
#undef STAGE_A
#undef STAGE_B
#undef GL8

#pragma unroll
  for (int mi = 0; mi < 8; ++mi) {
#pragma unroll
    for (int ni = 0; ni < 4; ++ni) {
#pragma unroll
      for (int r = 0; r < 4; ++r) {
        int row = m0 + wm * 128 + mi * 16 + quad * 4 + r;
        int col = n0 + wn * 64 + ni * 16 + l16;
        if (OUTF32)
          ((float*)Cp)[(size_t)row * N + col] = acc[mi][ni][r];
        else
          ((u16*)Cp)[(size_t)row * N + col] = f2b(acc[mi][ni][r]);
      }
    }
  }
}

// -------- gemm2_comb: 128x128 m97 GEMM with FUSED split-combine A-staging ----
// A[row][col] = (Op0+Op1)[row][col] * 1/(Lp0+Lp1)(row, h=col>>8), bf16 (RTNE --
// bit-identical to the old combine's f2b). A-tile k-span is 32 cols, h uniform
// per tile (32|256). A reg-staged (fp32 loads + cvt_pk + ds_write_b128,
// contiguous->conflict-free); B stays global_load_lds. Removes the combine
// kernel, the Ao buffer, and a launch.
__global__ __launch_bounds__(256, 2) void gemm2_comb(
    const float* __restrict__ Op0, const float* __restrict__ Op1,
    const float* __restrict__ Lp0, const float* __restrict__ Lp1,
    const u16* __restrict__ B, float* __restrict__ C, int M, int N, int K) {
  __shared__ u16 As[128 * 32];
  __shared__ u16 Bs[128 * 32];
  int m0 = blockIdx.y * 128, n0 = blockIdx.x * 128;
  int tid = threadIdx.x;
  int lane = tid & 63, wave = tid >> 6;
  int wy = wave >> 1, wx = wave & 1;
  int quad = lane >> 4, l16 = lane & 15;
  f32x4 acc[4][4] = {};
  for (int k0 = 0; k0 < K; k0 += 32) {
    int h = k0 >> 8;  // head index, uniform across this 32-col tile
#pragma unroll
    for (int i = 0; i < 2; ++i) {
      int chunk = i * 256 + tid;
      int row = chunk >> 2, col = (chunk & 3) << 3;
      size_t grow = (size_t)(m0 + row);
      const float* p0 = Op0 + grow * AON_ + k0 + col;
      const float* p1 = Op1 + grow * AON_ + k0 + col;
      float4 a0 = *(const float4*)p0;
      float4 a1 = *(const float4*)(p0 + 4);
      float4 c0 = *(const float4*)p1;
      float4 c1 = *(const float4*)(p1 + 4);
      int bb = (int)(grow >> 11), s = (int)(grow & 2047);
      size_t li = ((size_t)(bb * H_ + h)) * S_ + s;
      float inv = 1.0f / (Lp0[li] + Lp1[li]);
      union { short8 s8; unsigned int d[4]; } u;
      u.d[0] = cvt_pk_bf16((a0.x + c0.x) * inv, (a0.y + c0.y) * inv);
      u.d[1] = cvt_pk_bf16((a0.z + c0.z) * inv, (a0.w + c0.w) * inv);
      u.d[2] = cvt_pk_bf16((a1.x + c1.x) * inv, (a1.y + c1.y) * inv);
      u.d[3] = cvt_pk_bf16((a1.z + c1.z) * inv, (a1.w + c1.w) * inv);
      *(short8*)(As + chunk * 8) = u.s8;
    }
#pragma unroll
    for (int i = 0; i < 2; ++i) {
      int chunk = i * 256 + tid;
      int row = chunk >> 2, col = (chunk & 3) << 3;
      __builtin_amdgcn_global_load_lds(
          (const __attribute__((address_space(1))) void*)(B + (size_t)(n0 + row) * K + k0 + col),
          (__attribute__((address_space(3))) void*)(Bs + chunk * 8), 16, 0, 0);
    }
    __syncthreads();
    short8 af[4], bf[4];
#pragma unroll
    for (int mi = 0; mi < 4; ++mi)
      af[mi] = *(const short8*)(As + (wy * 64 + mi * 16 + l16) * 32 + quad * 8);
#pragma unroll
    for (int ni = 0; ni < 4; ++ni)
      bf[ni] = *(const short8*)(Bs + (wx * 64 + ni * 16 + l16) * 32 + quad * 8);
#pragma unroll
    for (int mi = 0; mi < 4; ++mi)
#pragma unroll
      for (int ni = 0; ni < 4; ++ni)
        acc[mi][ni] = __builtin_amdgcn_mfma_f32_16x16x32_bf16(af[mi], bf[ni], acc[mi][ni], 0, 0, 0);
    __syncthreads();
  }
#pragma unroll
  for (int mi = 0; mi < 4; ++mi) {
#pragma unroll
    for (int ni = 0; ni < 4; ++ni) {
#pragma unroll
      for (int r = 0; r < 4; ++r) {
        int row = m0 + wy * 64 + mi * 16 + quad * 4 + r;
        int col = n0 + wx * 64 + ni * 16 + l16;
        C[(size_t)row * N + col] = acc[mi][ni][r];
      }
    }
  }
}

// ---------------- rope_tv: RoPE (blocks 0..511) + V transpose (512..1535) -----
__global__ void rope_tv_kernel(const u16* __restrict__ qkv, const float* __restrict__ cs,
                               const float* __restrict__ sn, u16* __restrict__ Qr,
                               u16* __restrict__ Kr, u16* __restrict__ Vt) {
  __shared__ u16 tile[64][72];
  int bx = blockIdx.x;
  int t = threadIdx.x;
  if (bx < 512) {  // RoPE v2: paired halves, ushort4 vectorized
    int row = bx * 8 + (t >> 5);
    int d0 = (t & 31) * 4;
    int b = row >> 11, s = row & 2047;
    const u16* qrow = qkv + (size_t)row * QKVN_;
    float4 c4 = *(const float4*)(cs + (size_t)row * D_ + d0);
    float4 s4 = *(const float4*)(sn + (size_t)row * D_ + d0);
    float c[4] = {c4.x, c4.y, c4.z, c4.w};
    float sv[4] = {s4.x, s4.y, s4.z, s4.w};
#pragma unroll
    for (int h = 0; h < H_ + KVH_; ++h) {
      const u16* src = qrow + (h < H_ ? h * D_ : 2048 + (h - H_) * D_);
      us4 lo = *(const us4*)(src + d0);
      us4 hi = *(const us4*)(src + 128 + d0);
      us4 olo, ohi;
#pragma unroll
      for (int j = 0; j < 4; ++j) {
        float xl = b2f(lo[j]), xh = b2f(hi[j]);
        olo[j] = f2b(xl * c[j] - xh * sv[j]);
        ohi[j] = f2b(xh * c[j] + xl * sv[j]);
      }
      u16* dst = (h < H_)
          ? Qr + ((size_t)(b * H_ + h) * S_ + s) * D_
          : Kr + ((size_t)(b * KVH_ + (h - H_)) * S_ + s) * D_;
      *(us4*)(dst + d0) = olo;
      *(us4*)(dst + 128 + d0) = ohi;
    }
    return;
  }
  // V transpose
  int tt = bx - 512;
  int g = tt >> 7;             // b*KVH+kvh
  int rem = tt & 127;
  int s0 = (rem >> 2) * 64;
  int d0 = (rem & 3) * 64;
  int b = g >> 2, kvh = g & 3;
#pragma unroll
  for (int i = 0; i < 8; ++i) {
    int e = i * 256 + t;
    int r = e >> 5, c = (e & 31) * 2;
    unsigned int v = *(const unsigned int*)(&qkv[(size_t)(b * S_ + s0 + r) * QKVN_ +
                                                 3072 + kvh * D_ + d0 + c]);
    tile[r][c] = (u16)v;
    tile[r][c + 1] = (u16)(v >> 16);
  }
  __syncthreads();
#pragma unroll
  for (int i = 0; i < 8; ++i) {
    int e = i * 256 + t;
    int orow = e >> 5, ocol = (e & 31) * 2;
    unsigned int w = (unsigned int)tile[ocol][orow] |
                     ((unsigned int)tile[ocol + 1][orow] << 16);
    *(unsigned int*)(&Vt[((size_t)g * D_ + d0 + orow) * S_ + s0 + ocol]) = w;
  }
}

// ---------------- flash attention v8c (proven 78.3us): unchanged ----------------
__global__ __launch_bounds__(256, 2) void attn_kernel(
    const u16* __restrict__ Qr, const u16* __restrict__ Kr, const u16* __restrict__ Vt,
    float* __restrict__ Op0, float* __restrict__ Op1,
    float* __restrict__ Lp0, float* __restrict__ Lp1) {
  __shared__ u16 Ks[2][32 * 256]; // 2x16 KB, chunk-swizzled (^ sw(row))
  __shared__ u16 Vs[2][32 * 256]; // 2x16 KB, chunk-swizzled (^ (d>>1)&3)
  int bx = blockIdx.x;
  int h = bx & 7;                 // XCD pin: round-robin dispatch -> XCD = bx%8
  int u = bx >> 4;
  int sp = (bx >> 3) & 1;
  int kvh = h >> 1;  // N_REP = 2
  int tid = threadIdx.x, wave = tid >> 6, lane = tid & 63;
  int quad = lane >> 4, l16 = lane & 15;
  float* Op = sp ? Op1 : Op0;
  float* Lp = sp ? Lp1 : Lp0;
  int ksrc_s[4], ksrc_c[4], vsrc_d[4], vsrc_s[4];
#pragma unroll
  for (int i = 0; i < 4; ++i) {
    int p = i * 256 + tid;
    int sK = p >> 5;
    ksrc_s[i] = sK;
    ksrc_c[i] = (p & 31) ^ ((sK & 3) | (((sK >> 3) & 1) << 2));
    vsrc_d[i] = p >> 2;
    vsrc_s[i] = (p & 3) ^ ((p >> 3) & 3);
  }
  // K-fragment read geometry (swapped-QK, permuted rows):
  const int kg = l16 >> 2, ka = l16 & 3;
  const int srow0 = 8 * kg + ka;           // n=0; n=1 adds 4
  const int ksw = ka | ((kg & 1) << 2);    // sw(srow), same for n=0,1

  for (int part = 0; part < 2; ++part) {
    int b = part;
    int qt = (part == 0) ? u : (31 - u);
    int q0 = qt * 64;
    int beg = sp ? (qt + 1) : 0;
    int end = sp ? (2 * qt + 2) : (qt + 1);
    const u16* Qbase = Qr + ((size_t)(b * H_ + h) * S_ + q0 + wave * 16 + l16) * D_;
    short8 qf[8];
#pragma unroll
    for (int kk = 0; kk < 8; ++kk)
      qf[kk] = *(const short8*)(Qbase + kk * 32 + quad * 8);
    const u16* Kbase = Kr + (size_t)(b * KVH_ + kvh) * S_ * D_;
    const u16* Vbase = Vt + (size_t)(b * KVH_ + kvh) * D_ * S_;
    float lp = 0.f;
    f32x4 o_acc[16] = {};
    const int qq = q0 + wave * 16 + l16;

#define STAGE(KT, BUF)                                                                   \
    {                                                                                    \
      int k0s = (KT) * 32;                                                               \
      _Pragma("unroll") for (int i = 0; i < 4; ++i) {                                    \
        int p = i * 256 + tid;                                                           \
        __builtin_amdgcn_global_load_lds(                                                \
            (const __attribute__((address_space(1))) void*)(Kbase +                      \
                (size_t)(k0s + ksrc_s[i]) * D_ + ksrc_c[i] * 8),                         \
            (__attribute__((address_space(3))) void*)(&Ks[BUF][0] + p * 8), 16, 0, 0);   \
      }                                                                                  \
      _Pragma("unroll") for (int i = 0; i < 4; ++i) {                                    \
        int p = i * 256 + tid;                                                           \
        __builtin_amdgcn_global_load_lds(                                                \
            (const __attribute__((address_space(1))) void*)(Vbase +                      \
                (size_t)vsrc_d[i] * S_ + k0s + vsrc_s[i] * 8),                           \
            (__attribute__((address_space(3))) void*)(&Vs[BUF][0] + p * 8), 16, 0, 0);   \
      }                                                                                  \
    }

    STAGE(beg, 0);
    __syncthreads();
    for (int kt = beg; kt < end; ++kt) {
      int k0 = kt * 32;
      int cur = (kt - beg) & 1;
      if (kt + 1 < end) STAGE(kt + 1, cur ^ 1);
      // S^T = K Q^T (A = permuted K-tile, B = Q)
      f32x4 sacc[2] = {};
      __builtin_amdgcn_s_setprio(1);
#pragma unroll
      for (int n = 0; n < 2; ++n) {
        const u16* kb = &Ks[cur][0] + (srow0 + 4 * n) * 256;
#pragma unroll
        for (int kk = 0; kk < 8; ++kk) {
          int phys = (kk * 4 + quad) ^ ksw;
          short8 kfr = *(const short8*)(kb + phys * 8);
          sacc[n] = __builtin_amdgcn_mfma_f32_16x16x32_bf16(kfr, qf[kk], sacc[n], 0, 0, 0);
        }
      }
      __builtin_amdgcn_s_setprio(0);
      // fused softcap+softmax via exp2: E = 2^(s*0.0025*log2e), ee = 2^(-100*log2e*rcp(E+1))
      bool full = (k0 + 31 <= q0 + wave * 16);  // wave-uniform
#pragma unroll
      for (int n = 0; n < 2; ++n) {
#pragma unroll
        for (int r = 0; r < 4; ++r) {
          float E = exp2_raw(sacc[n][r] * 0.0036067376f);
          float ee = exp2_raw(__frcp_rn(E + 1.0f) * -144.2695041f);
          if (!full) {
            int key = k0 + 8 * quad + 4 * n + r;   // lane holds keys 8*quad + 4n + r
            ee = (key <= qq) ? ee : 0.0f;
          }
          lp += ee;
          sacc[n][r] = ee;
        }
      }
      // pack P in-register: frag elem j = key 8*quad+j, j = 4n+r
      union { short8 s8; unsigned int d[4]; } pu;
      pu.d[0] = cvt_pk_bf16(sacc[0][0], sacc[0][1]);
      pu.d[1] = cvt_pk_bf16(sacc[0][2], sacc[0][3]);
      pu.d[2] = cvt_pk_bf16(sacc[1][0], sacc[1][1]);
      pu.d[3] = cvt_pk_bf16(sacc[1][2], sacc[1][3]);
      short8 pa = pu.s8;
      // O += P V  (pa is PV's A-fragment directly; no LDS round-trip)
      __builtin_amdgcn_s_setprio(1);
#pragma unroll
      for (int dt = 0; dt < 16; ++dt) {
        int d = dt * 16 + l16;
        int phys = quad ^ ((d >> 1) & 3);
        short8 vb = *(const short8*)(&Vs[cur][0] + d * 32 + phys * 8);
        o_acc[dt] = __builtin_amdgcn_mfma_f32_16x16x32_bf16(pa, vb, o_acc[dt], 0, 0, 0);
      }
      __builtin_amdgcn_s_setprio(0);
      __syncthreads();  // buffer handoff (prefetch long since landed)
    }
#undef STAGE
    // denominator partial: lane holds sum for q=l16 over its 8 keys/iter; reduce quads
    lp += __shfl_xor(lp, 16, 64);
    lp += __shfl_xor(lp, 32, 64);
    if (lane < 16)
      Lp[((size_t)(b * H_ + h)) * S_ + q0 + wave * 16 + lane] = lp;
    // unnormalized fp32 partial O (row q = quad*4+r, col d = dt*16+l16)
#pragma unroll
    for (int dt = 0; dt < 16; ++dt)
#pragma unroll
      for (int r = 0; r < 4; ++r) {
        int row = b * S_ + q0 + wave * 16 + quad * 4 + r;
        int col = h * D_ + dt * 16 + l16;
        Op[(size_t)row * AON_ + col] = o_acc[dt][r];
      }
  }
}

extern "C" void kernel_launch(void* const* d_in, const int* in_sizes, int n_in,
                              void* d_out, int out_size, void* d_ws, size_t ws_size,
                              hipStream_t stream) {
  const float* hidden = (const float*)d_in[0];
  const float* cosp = (const float*)d_in[1];
  const float* sinp = (const float*)d_in[2];
  const float* Wq = (const float*)d_in[4];
  const float* Wk = (const float*)d_in[5];
  const float* Wv = (const float*)d_in[6];
  const float* Wo = (const float*)d_in[7];

  u16* hs  = (u16*)d_ws;                              // 4096 x 2304 (dead after gemm1)
  u16* WT  = hs  + (size_t)4096 * HID_;               // 4096 x 2304 (dead after gemm1)
  u16* WoT = WT  + (size_t)4096 * HID_;               // 2304 x 2048 (live till gemm2)
  u16* qkv = WoT + (size_t)HID_ * AON_;               // 4096 x 4096 (dead after rope_tv)
  u16* Qr  = qkv + (size_t)4096 * QKVN_;              // B,H,S,D
  u16* Kr  = Qr  + (size_t)B_ * H_ * S_ * D_;         // B,KVH,S,D
  u16* Vt  = Kr  + (size_t)B_ * KVH_ * S_ * D_;       // B,KVH,D,S
  u16* Ao  = Vt  + (size_t)B_ * KVH_ * S_ * D_;       // (unused now, slot kept)
  float* Lp0 = (float*)(Ao + (size_t)4096 * AON_);    // 2*8*2048 fp32
  float* Lp1 = Lp0 + (size_t)B_ * H_ * S_;            // 2*8*2048 fp32
  float* Op0 = (float*)hs;    // hs+WT region: 37.7 MB available >= 33.5
  float* Op1 = (float*)qkv;   // qkv region: 33.5 MB, exact fit

  prep_kernel<<<2112, 256, 0, stream>>>(
      hidden, Wq, Wk, Wv, Wo, hs,
      WT, WT + (size_t)2048 * HID_, WT + (size_t)3072 * HID_, WoT);
  gemm_bt8<0><<<dim3(16, 16), 512, 0, stream>>>(hs, WT, qkv, 4096, QKVN_, HID_);
  rope_tv_kernel<<<1536, 256, 0, stream>>>(qkv, cosp, sinp, Qr, Kr, Vt);
  attn_kernel<<<dim3(512), 256, 0, stream>>>(Qr, Kr, Vt, Op0, Op1, Lp0, Lp1);
  gemm2_comb<<<dim3(18, 32), 256, 0, stream>>>(
      Op0, Op1, Lp0, Lp1, WoT, (float*)d_out, 4096, HID_, 2048);
}

// Round 15
// 391.620 us; speedup vs baseline: 1.1722x; 1.1722x over previous
//
#include <hip/hip_runtime.h>

typedef unsigned short u16;
typedef __attribute__((ext_vector_type(8))) short short8;
typedef __attribute__((ext_vector_type(4))) float f32x4;
typedef __attribute__((ext_vector_type(4))) unsigned short us4;

constexpr int B_ = 2;
constexpr int H_ = 8;
constexpr int KVH_ = 4;
constexpr int S_ = 2048;
constexpr int D_ = 256;
constexpr int HID_ = 2304;
constexpr int QKVN_ = 4096;   // 2048 q + 1024 k + 1024 v
constexpr int AON_ = 2048;    // H_*D_

__device__ __forceinline__ float b2f(u16 u) {
  union { float f; unsigned int i; } x; x.i = ((unsigned int)u) << 16; return x.f;
}
__device__ __forceinline__ u16 f2b(float f) {
  unsigned int x = __float_as_uint(f);
  unsigned int r = (x + 0x7fffu + ((x >> 16) & 1u)) >> 16;
  return (u16)r;
}
// raw v_exp_f32: computes 2^x (no ln2 conversion mul)
__device__ __forceinline__ float exp2_raw(float x) {
  float r;
  asm("v_exp_f32 %0, %1" : "=v"(r) : "v"(x));
  return r;
}
// packed f32x2 -> bf16x2 (RTNE, identical result to f2b pair)
__device__ __forceinline__ unsigned int cvt_pk_bf16(float lo, float hi) {
  unsigned int r;
  asm("v_cvt_pk_bf16_f32 %0, %1, %2" : "=v"(r) : "v"(lo), "v"(hi));
  return r;
}

// ---------------- prep: cast + 4 weight transposes, grid-strided ----
__global__ void prep_kernel(const float* __restrict__ hidden,
                            const float* __restrict__ s0, const float* __restrict__ s1,
                            const float* __restrict__ s2, const float* __restrict__ s3,
                            u16* __restrict__ hsOut,
                            u16* __restrict__ d0, u16* __restrict__ d1,
                            u16* __restrict__ d2, u16* __restrict__ d3) {
  __shared__ float tile[64][65];
  int t = threadIdx.x;
  for (int bx = blockIdx.x; bx < 12672; bx += gridDim.x) {
    if (bx < 9216) {  // cast fp32 -> bf16
      size_t i = ((size_t)bx * 256 + t) * 4;
      float4 v = *(const float4*)(hidden + i);
      unsigned int lo = (unsigned int)f2b(v.x) | ((unsigned int)f2b(v.y) << 16);
      unsigned int hi = (unsigned int)f2b(v.z) | ((unsigned int)f2b(v.w) << 16);
      uint2 o; o.x = lo; o.y = hi;
      *(uint2*)(hsOut + i) = o;
      continue;
    }
    int tt = bx - 9216;
    const float* src; u16* dst; int R, C, cx, cy;
    if (tt < 1152)              { src = s0; dst = d0; R = 2304; C = 2048; cx = tt & 31; cy = tt >> 5; }
    else if ((tt -= 1152) < 576){ src = s1; dst = d1; R = 2304; C = 1024; cx = tt & 15; cy = tt >> 4; }
    else if ((tt -= 576) < 576) { src = s2; dst = d2; R = 2304; C = 1024; cx = tt & 15; cy = tt >> 4; }
    else { tt -= 576;             src = s3; dst = d3; R = 2048; C = 2304; cx = tt % 36; cy = tt / 36; }
    int r0 = cy * 64, c0 = cx * 64;
#pragma unroll
    for (int i = 0; i < 16; ++i) {
      int e = i * 256 + t;
      int r = e >> 6, c = e & 63;
      tile[r][c] = src[(size_t)(r0 + r) * C + (c0 + c)];
    }
    __syncthreads();
#pragma unroll
    for (int i = 0; i < 8; ++i) {
      int e = i * 256 + t;
      int orow = e >> 5;
      int ocol = (e & 31) * 2;
      unsigned int w = (unsigned int)f2b(tile[ocol][orow]) |
                       ((unsigned int)f2b(tile[ocol + 1][orow]) << 16);
      *(unsigned int*)(&dst[(size_t)(c0 + orow) * R + (r0 + ocol)]) = w;
    }
    __syncthreads();  // protect shared tile before next iteration's fill
  }
}

// ---------------- 256x256-tile 8-wave 4-phase/K-tile bf16 GEMM (gemm1) ----
template <int OUTF32>
__global__ __launch_bounds__(512, 2) void gemm_bt8(
    const u16* __restrict__ A, const u16* __restrict__ B, void* __restrict__ Cp,
    int M, int N, int K) {
  __shared__ u16 lds[2][2][2][8192];  // [buf][0=A,1=B][half(128 rows)][16 KiB]
  const int tid = threadIdx.x;
  const int lane = tid & 63;
  const int wave = tid >> 6;
  const int wm = wave >> 2, wn = wave & 3;       // 2 (M) x 4 (N) waves
  const int quad = lane >> 4, l16 = lane & 15;
  const int m0 = blockIdx.y * 256, n0 = blockIdx.x * 256;
  const int nt = K >> 6;  // K-tiles of 64

  const int sub = tid >> 6;
  const int rr = (tid >> 2) & 15;
  const int cc = ((tid & 3) * 8) ^ ((rr & 8) ? 16 : 0);
  const int r_rel = (sub >> 1) * 16 + rr;   // 0..63 row within region
  const int ccol = (sub & 1) * 32 + cc;     // 0..63 k-col (pre-inverse-swizzled)
  const u16* Asrc = A + (size_t)(m0 + r_rel) * K + ccol;
  const u16* Bsrc = B + (size_t)(n0 + r_rel) * K + ccol;
  const int ldsc = tid * 8;  // u16 index of this thread's 16 B chunk in a region

  const int fr_off = l16 * 64 + (((quad * 8) ^ ((l16 & 8) ? 16 : 0)) << 1);

#define GL8(src, dst)                                                                  \
  __builtin_amdgcn_global_load_lds((const __attribute__((address_space(1))) void*)(src), \
                                   (__attribute__((address_space(3))) void*)(dst), 16, 0, 0)
#define STAGE_A(bf, kt, qp) {                                                          \
    const u16* _s = Asrc + (size_t)(kt) * 64;                                          \
    GL8(_s + (size_t)((qp) * 64) * K,       &lds[bf][0][0][(qp) * 4096 + ldsc]);       \
    GL8(_s + (size_t)(128 + (qp) * 64) * K, &lds[bf][0][1][(qp) * 4096 + ldsc]); }
#define STAGE_B(bf, kt, hf) {                                                          \
    const u16* _s = Bsrc + (size_t)(kt) * 64;                                          \
    GL8(_s + (size_t)((hf) * 128) * K,      &lds[bf][1][hf][ldsc]);                    \
    GL8(_s + (size_t)((hf) * 128 + 64) * K, &lds[bf][1][hf][4096 + ldsc]); }
#define LDA(bf, mi, kk) \
  (*(const short8*)((const char*)&lds[bf][0][wm][0] + (mi) * 2048 + (kk) * 1024 + fr_off))
#define LDB(bf, ni, kk) \
  (*(const short8*)((const char*)&lds[bf][1][wn >> 1][0] + ((wn & 1) * 4 + (ni)) * 2048 + (kk) * 1024 + fr_off))

  f32x4 acc[8][4] = {};
  short8 bfr[4][2], af[2][2];

  STAGE_B(0, 0, 0); STAGE_B(0, 0, 1); STAGE_A(0, 0, 0); STAGE_A(0, 0, 1);
  STAGE_B(1, 1, 0); STAGE_B(1, 1, 1); STAGE_A(1, 1, 0);
  asm volatile("s_waitcnt vmcnt(6)" ::: "memory");
  __builtin_amdgcn_s_barrier();

#define PHASE(q, STG, VMW)                                                             \
    _Pragma("unroll") for (int i = 0; i < 2; ++i)                                      \
      _Pragma("unroll") for (int kk = 0; kk < 2; ++kk) af[i][kk] = LDA(c, 2 * (q) + i, kk); \
    STG; VMW;                                                                          \
    __builtin_amdgcn_s_barrier();                                                      \
    asm volatile("s_waitcnt lgkmcnt(0)" ::: "memory");                                 \
    __builtin_amdgcn_sched_barrier(0);                                                 \
    __builtin_amdgcn_s_setprio(1);                                                     \
    _Pragma("unroll") for (int i = 0; i < 2; ++i)                                      \
      _Pragma("unroll") for (int ni = 0; ni < 4; ++ni)                                 \
        _Pragma("unroll") for (int kk = 0; kk < 2; ++kk)                               \
          acc[2 * (q) + i][ni] = __builtin_amdgcn_mfma_f32_16x16x32_bf16(              \
              af[i][kk], bfr[ni][kk], acc[2 * (q) + i][ni], 0, 0, 0);                  \
    __builtin_amdgcn_s_setprio(0);                                                     \
    __builtin_amdgcn_s_barrier();

  for (int T = 0; T < nt; ++T) {
    const int c = T & 1;
#pragma unroll
    for (int ni = 0; ni < 4; ++ni)
#pragma unroll
      for (int kk = 0; kk < 2; ++kk) bfr[ni][kk] = LDB(c, ni, kk);
    PHASE(0, if (T + 1 < nt) STAGE_A(c ^ 1, T + 1, 1), )
    PHASE(1, if (T + 2 < nt) STAGE_B(c, T + 2, 0), )
    PHASE(2, if (T + 2 < nt) STAGE_B(c, T + 2, 1), )
    PHASE(3, if (T + 2 < nt) STAGE_A(c, T + 2, 0),
          if (T + 2 >= nt) { asm volatile("s_waitcnt vmcnt(0)" ::: "memory"); }
          else             { asm volatile("s_waitcnt vmcnt(6)" ::: "memory"); })
  }
#undef PHASE
#undef LDA
#undef LDB
#undef STAGE_A
#undef STAGE_B
#undef GL8

#pragma unroll
  for (int mi = 0; mi < 8; ++mi) {
#pragma unroll
    for (int ni = 0; ni < 4; ++ni) {
#pragma unroll
      for (int r = 0; r < 4; ++r) {
        int row = m0 + wm * 128 + mi * 16 + quad * 4 + r;
        int col = n0 + wn * 64 + ni * 16 + l16;
        if (OUTF32)
          ((float*)Cp)[(size_t)row * N + col] = acc[mi][ni][r];
        else
          ((u16*)Cp)[(size_t)row * N + col] = f2b(acc[mi][ni][r]);
      }
    }
  }
}

// ---------------- m97-style 128x128 bf16 GEMM (gemm2) ----
template <int OUTF32>
__global__ __launch_bounds__(256, 2) void gemm_bt(
    const u16* __restrict__ A, const u16* __restrict__ B, void* __restrict__ Cp,
    int M, int N, int K) {
  __shared__ u16 As[128 * 32];
  __shared__ u16 Bs[128 * 32];
  int m0 = blockIdx.y * 128, n0 = blockIdx.x * 128;
  int tid = threadIdx.x;
  int lane = tid & 63, wave = tid >> 6;
  int wy = wave >> 1, wx = wave & 1;
  int quad = lane >> 4, l16 = lane & 15;
  f32x4 acc[4][4] = {};
  for (int k0 = 0; k0 < K; k0 += 32) {
#pragma unroll
    for (int i = 0; i < 2; ++i) {
      int chunk = i * 256 + tid;
      int row = chunk >> 2, col = (chunk & 3) << 3;
      __builtin_amdgcn_global_load_lds(
          (const __attribute__((address_space(1))) void*)(A + (size_t)(m0 + row) * K + k0 + col),
          (__attribute__((address_space(3))) void*)(As + chunk * 8), 16, 0, 0);
    }
#pragma unroll
    for (int i = 0; i < 2; ++i) {
      int chunk = i * 256 + tid;
      int row = chunk >> 2, col = (chunk & 3) << 3;
      __builtin_amdgcn_global_load_lds(
          (const __attribute__((address_space(1))) void*)(B + (size_t)(n0 + row) * K + k0 + col),
          (__attribute__((address_space(3))) void*)(Bs + chunk * 8), 16, 0, 0);
    }
    __syncthreads();
    short8 af[4], bf[4];
#pragma unroll
    for (int mi = 0; mi < 4; ++mi)
      af[mi] = *(const short8*)(As + (wy * 64 + mi * 16 + l16) * 32 + quad * 8);
#pragma unroll
    for (int ni = 0; ni < 4; ++ni)
      bf[ni] = *(const short8*)(Bs + (wx * 64 + ni * 16 + l16) * 32 + quad * 8);
#pragma unroll
    for (int mi = 0; mi < 4; ++mi)
#pragma unroll
      for (int ni = 0; ni < 4; ++ni)
        acc[mi][ni] = __builtin_amdgcn_mfma_f32_16x16x32_bf16(af[mi], bf[ni], acc[mi][ni], 0, 0, 0);
    __syncthreads();
  }
#pragma unroll
  for (int mi = 0; mi < 4; ++mi) {
#pragma unroll
    for (int ni = 0; ni < 4; ++ni) {
#pragma unroll
      for (int r = 0; r < 4; ++r) {
        int row = m0 + wy * 64 + mi * 16 + quad * 4 + r;
        int col = n0 + wx * 64 + ni * 16 + l16;
        if (OUTF32)
          ((float*)Cp)[(size_t)row * N + col] = acc[mi][ni][r];
        else
          ((u16*)Cp)[(size_t)row * N + col] = f2b(acc[mi][ni][r]);
      }
    }
  }
}

// ---------------- rope_tv: RoPE (blocks 0..511) + V transpose (512..1535) -----
__global__ void rope_tv_kernel(const u16* __restrict__ qkv, const float* __restrict__ cs,
                               const float* __restrict__ sn, u16* __restrict__ Qr,
                               u16* __restrict__ Kr, u16* __restrict__ Vt) {
  __shared__ u16 tile[64][72];
  int bx = blockIdx.x;
  int t = threadIdx.x;
  if (bx < 512) {  // RoPE v2: paired halves, ushort4 vectorized
    int row = bx * 8 + (t >> 5);
    int d0 = (t & 31) * 4;
    int b = row >> 11, s = row & 2047;
    const u16* qrow = qkv + (size_t)row * QKVN_;
    float4 c4 = *(const float4*)(cs + (size_t)row * D_ + d0);
    float4 s4 = *(const float4*)(sn + (size_t)row * D_ + d0);
    float c[4] = {c4.x, c4.y, c4.z, c4.w};
    float sv[4] = {s4.x, s4.y, s4.z, s4.w};
#pragma unroll
    for (int h = 0; h < H_ + KVH_; ++h) {
      const u16* src = qrow + (h < H_ ? h * D_ : 2048 + (h - H_) * D_);
      us4 lo = *(const us4*)(src + d0);
      us4 hi = *(const us4*)(src + 128 + d0);
      us4 olo, ohi;
#pragma unroll
      for (int j = 0; j < 4; ++j) {
        float xl = b2f(lo[j]), xh = b2f(hi[j]);
        olo[j] = f2b(xl * c[j] - xh * sv[j]);
        ohi[j] = f2b(xh * c[j] + xl * sv[j]);
      }
      u16* dst = (h < H_)
          ? Qr + ((size_t)(b * H_ + h) * S_ + s) * D_
          : Kr + ((size_t)(b * KVH_ + (h - H_)) * S_ + s) * D_;
      *(us4*)(dst + d0) = olo;
      *(us4*)(dst + 128 + d0) = ohi;
    }
    return;
  }
  // V transpose
  int tt = bx - 512;
  int g = tt >> 7;             // b*KVH+kvh
  int rem = tt & 127;
  int s0 = (rem >> 2) * 64;
  int d0 = (rem & 3) * 64;
  int b = g >> 2, kvh = g & 3;
#pragma unroll
  for (int i = 0; i < 8; ++i) {
    int e = i * 256 + t;
    int r = e >> 5, c = (e & 31) * 2;
    unsigned int v = *(const unsigned int*)(&qkv[(size_t)(b * S_ + s0 + r) * QKVN_ +
                                                 3072 + kvh * D_ + d0 + c]);
    tile[r][c] = (u16)v;
    tile[r][c + 1] = (u16)(v >> 16);
  }
  __syncthreads();
#pragma unroll
  for (int i = 0; i < 8; ++i) {
    int e = i * 256 + t;
    int orow = e >> 5, ocol = (e & 31) * 2;
    unsigned int w = (unsigned int)tile[ocol][orow] |
                     ((unsigned int)tile[ocol + 1][orow] << 16);
    *(unsigned int*)(&Vt[((size_t)g * D_ + d0 + orow) * S_ + s0 + ocol]) = w;
  }
}

// ---------------- flash attention v8c (proven 78.3us): unchanged ----------------
__global__ __launch_bounds__(256, 2) void attn_kernel(
    const u16* __restrict__ Qr, const u16* __restrict__ Kr, const u16* __restrict__ Vt,
    float* __restrict__ Op0, float* __restrict__ Op1,
    float* __restrict__ Lp0, float* __restrict__ Lp1) {
  __shared__ u16 Ks[2][32 * 256]; // 2x16 KB, chunk-swizzled (^ sw(row))
  __shared__ u16 Vs[2][32 * 256]; // 2x16 KB, chunk-swizzled (^ (d>>1)&3)
  int bx = blockIdx.x;
  int h = bx & 7;                 // XCD pin: round-robin dispatch -> XCD = bx%8
  int u = bx >> 4;
  int sp = (bx >> 3) & 1;
  int kvh = h >> 1;  // N_REP = 2
  int tid = threadIdx.x, wave = tid >> 6, lane = tid & 63;
  int quad = lane >> 4, l16 = lane & 15;
  float* Op = sp ? Op1 : Op0;
  float* Lp = sp ? Lp1 : Lp0;
  int ksrc_s[4], ksrc_c[4], vsrc_d[4], vsrc_s[4];
#pragma unroll
  for (int i = 0; i < 4; ++i) {
    int p = i * 256 + tid;
    int sK = p >> 5;
    ksrc_s[i] = sK;
    ksrc_c[i] = (p & 31) ^ ((sK & 3) | (((sK >> 3) & 1) << 2));
    vsrc_d[i] = p >> 2;
    vsrc_s[i] = (p & 3) ^ ((p >> 3) & 3);
  }
  // K-fragment read geometry (swapped-QK, permuted rows):
  const int kg = l16 >> 2, ka = l16 & 3;
  const int srow0 = 8 * kg + ka;           // n=0; n=1 adds 4
  const int ksw = ka | ((kg & 1) << 2);    // sw(srow), same for n=0,1

  for (int part = 0; part < 2; ++part) {
    int b = part;
    int qt = (part == 0) ? u : (31 - u);
    int q0 = qt * 64;
    int beg = sp ? (qt + 1) : 0;
    int end = sp ? (2 * qt + 2) : (qt + 1);
    const u16* Qbase = Qr + ((size_t)(b * H_ + h) * S_ + q0 + wave * 16 + l16) * D_;
    short8 qf[8];
#pragma unroll
    for (int kk = 0; kk < 8; ++kk)
      qf[kk] = *(const short8*)(Qbase + kk * 32 + quad * 8);
    const u16* Kbase = Kr + (size_t)(b * KVH_ + kvh) * S_ * D_;
    const u16* Vbase = Vt + (size_t)(b * KVH_ + kvh) * D_ * S_;
    float lp = 0.f;
    f32x4 o_acc[16] = {};
    const int qq = q0 + wave * 16 + l16;

#define STAGE(KT, BUF)                                                                   \
    {                                                                                    \
      int k0s = (KT) * 32;                                                               \
      _Pragma("unroll") for (int i = 0; i < 4; ++i) {                                    \
        int p = i * 256 + tid;                                                           \
        __builtin_amdgcn_global_load_lds(                                                \
            (const __attribute__((address_space(1))) void*)(Kbase +                      \
                (size_t)(k0s + ksrc_s[i]) * D_ + ksrc_c[i] * 8),                         \
            (__attribute__((address_space(3))) void*)(&Ks[BUF][0] + p * 8), 16, 0, 0);   \
      }                                                                                  \
      _Pragma("unroll") for (int i = 0; i < 4; ++i) {                                    \
        int p = i * 256 + tid;                                                           \
        __builtin_amdgcn_global_load_lds(                                                \
            (const __attribute__((address_space(1))) void*)(Vbase +                      \
                (size_t)vsrc_d[i] * S_ + k0s + vsrc_s[i] * 8),                           \
            (__attribute__((address_space(3))) void*)(&Vs[BUF][0] + p * 8), 16, 0, 0);   \
      }                                                                                  \
    }

    STAGE(beg, 0);
    __syncthreads();
    for (int kt = beg; kt < end; ++kt) {
      int k0 = kt * 32;
      int cur = (kt - beg) & 1;
      if (kt + 1 < end) STAGE(kt + 1, cur ^ 1);
      // S^T = K Q^T (A = permuted K-tile, B = Q)
      f32x4 sacc[2] = {};
      __builtin_amdgcn_s_setprio(1);
#pragma unroll
      for (int n = 0; n < 2; ++n) {
        const u16* kb = &Ks[cur][0] + (srow0 + 4 * n) * 256;
#pragma unroll
        for (int kk = 0; kk < 8; ++kk) {
          int phys = (kk * 4 + quad) ^ ksw;
          short8 kfr = *(const short8*)(kb + phys * 8);
          sacc[n] = __builtin_amdgcn_mfma_f32_16x16x32_bf16(kfr, qf[kk], sacc[n], 0, 0, 0);
        }
      }
      __builtin_amdgcn_s_setprio(0);
      // fused softcap+softmax via exp2: E = 2^(s*0.0025*log2e), ee = 2^(-100*log2e*rcp(E+1))
      bool full = (k0 + 31 <= q0 + wave * 16);  // wave-uniform
#pragma unroll
      for (int n = 0; n < 2; ++n) {
#pragma unroll
        for (int r = 0; r < 4; ++r) {
          float E = exp2_raw(sacc[n][r] * 0.0036067376f);
          float ee = exp2_raw(__frcp_rn(E + 1.0f) * -144.2695041f);
          if (!full) {
            int key = k0 + 8 * quad + 4 * n + r;   // lane holds keys 8*quad + 4n + r
            ee = (key <= qq) ? ee : 0.0f;
          }
          lp += ee;
          sacc[n][r] = ee;
        }
      }
      // pack P in-register: frag elem j = key 8*quad+j, j = 4n+r
      union { short8 s8; unsigned int d[4]; } pu;
      pu.d[0] = cvt_pk_bf16(sacc[0][0], sacc[0][1]);
      pu.d[1] = cvt_pk_bf16(sacc[0][2], sacc[0][3]);
      pu.d[2] = cvt_pk_bf16(sacc[1][0], sacc[1][1]);
      pu.d[3] = cvt_pk_bf16(sacc[1][2], sacc[1][3]);
      short8 pa = pu.s8;
      // O += P V  (pa is PV's A-fragment directly; no LDS round-trip)
      __builtin_amdgcn_s_setprio(1);
#pragma unroll
      for (int dt = 0; dt < 16; ++dt) {
        int d = dt * 16 + l16;
        int phys = quad ^ ((d >> 1) & 3);
        short8 vb = *(const short8*)(&Vs[cur][0] + d * 32 + phys * 8);
        o_acc[dt] = __builtin_amdgcn_mfma_f32_16x16x32_bf16(pa, vb, o_acc[dt], 0, 0, 0);
      }
      __builtin_amdgcn_s_setprio(0);
      __syncthreads();  // buffer handoff (prefetch long since landed)
    }
#undef STAGE
    // denominator partial: lane holds sum for q=l16 over its 8 keys/iter; reduce quads
    lp += __shfl_xor(lp, 16, 64);
    lp += __shfl_xor(lp, 32, 64);
    if (lane < 16)
      Lp[((size_t)(b * H_ + h)) * S_ + q0 + wave * 16 + lane] = lp;
    // unnormalized fp32 partial O (row q = quad*4+r, col d = dt*16+l16)
#pragma unroll
    for (int dt = 0; dt < 16; ++dt)
#pragma unroll
      for (int r = 0; r < 4; ++r) {
        int row = b * S_ + q0 + wave * 16 + quad * 4 + r;
        int col = h * D_ + dt * 16 + l16;
        Op[(size_t)row * AON_ + col] = o_acc[dt][r];
      }
  }
}

// ---------------- combine splits: grid-strided (G11), 2048 blocks ----------------
__global__ void combine_kernel(const float* __restrict__ Op0, const float* __restrict__ Op1,
                               const float* __restrict__ Lp0, const float* __restrict__ Lp1,
                               u16* __restrict__ Ao) {
  for (size_t idx = (size_t)blockIdx.x * 256 + threadIdx.x; idx < (size_t)2097152;
       idx += (size_t)gridDim.x * 256) {
    size_t row = idx >> 9;
    int c4 = ((int)idx & 511) * 4;
    const float4 a = *(const float4*)(Op0 + row * AON_ + c4);
    const float4 b4 = *(const float4*)(Op1 + row * AON_ + c4);
    int b = (int)(row >> 11), s = (int)row & 2047;
    int h = c4 >> 8;
    size_t li = ((size_t)(b * H_ + h)) * S_ + s;
    float inv = 1.0f / (Lp0[li] + Lp1[li]);
    unsigned int lo = (unsigned int)f2b((a.x + b4.x) * inv) | ((unsigned int)f2b((a.y + b4.y) * inv) << 16);
    unsigned int hi = (unsigned int)f2b((a.z + b4.z) * inv) | ((unsigned int)f2b((a.w + b4.w) * inv) << 16);
    uint2 o; o.x = lo; o.y = hi;
    *(uint2*)(Ao + row * AON_ + c4) = o;
  }
}

extern "C" void kernel_launch(void* const* d_in, const int* in_sizes, int n_in,
                              void* d_out, int out_size, void* d_ws, size_t ws_size,
                              hipStream_t stream) {
  const float* hidden = (const float*)d_in[0];
  const float* cosp = (const float*)d_in[1];
  const float* sinp = (const float*)d_in[2];
  const float* Wq = (const float*)d_in[4];
  const float* Wk = (const float*)d_in[5];
  const float* Wv = (const float*)d_in[6];
  const float* Wo = (const float*)d_in[7];

  u16* hs  = (u16*)d_ws;                              // 4096 x 2304 (dead after gemm1)
  u16* WT  = hs  + (size_t)4096 * HID_;               // 4096 x 2304 (dead after gemm1)
  u16* WoT = WT  + (size_t)4096 * HID_;               // 2304 x 2048 (live till gemm2)
  u16* qkv = WoT + (size_t)HID_ * AON_;               // 4096 x 4096 (dead after rope_tv)
  u16* Qr  = qkv + (size_t)4096 * QKVN_;              // B,H,S,D
  u16* Kr  = Qr  + (size_t)B_ * H_ * S_ * D_;         // B,KVH,S,D
  u16* Vt  = Kr  + (size_t)B_ * KVH_ * S_ * D_;       // B,KVH,D,S
  u16* Ao  = Vt  + (size_t)B_ * KVH_ * S_ * D_;       // 4096 x 2048
  float* Lp0 = (float*)(Ao + (size_t)4096 * AON_);    // 2*8*2048 fp32
  float* Lp1 = Lp0 + (size_t)B_ * H_ * S_;            // 2*8*2048 fp32
  float* Op0 = (float*)hs;    // hs+WT region: 37.7 MB available >= 33.5
  float* Op1 = (float*)qkv;   // qkv region: 33.5 MB, exact fit

  prep_kernel<<<2112, 256, 0, stream>>>(
      hidden, Wq, Wk, Wv, Wo, hs,
      WT, WT + (size_t)2048 * HID_, WT + (size_t)3072 * HID_, WoT);
  gemm_bt8<0><<<dim3(16, 16), 512, 0, stream>>>(hs, WT, qkv, 4096, QKVN_, HID_);
  rope_tv_kernel<<<1536, 256, 0, stream>>>(qkv, cosp, sinp, Qr, Kr, Vt);
  attn_kernel<<<dim3(512), 256, 0, stream>>>(Qr, Kr, Vt, Op0, Op1, Lp0, Lp1);
  combine_kernel<<<2048, 256, 0, stream>>>(Op0, Op1, Lp0, Lp1, Ao);
  gemm_bt<1><<<dim3(18, 32), 256, 0, stream>>>(Ao, WoT, d_out, 4096, HID_, 2048);
}

// Round 16
// 384.406 us; speedup vs baseline: 1.1942x; 1.0188x over previous
//
#include <hip/hip_runtime.h>

typedef unsigned short u16;
typedef __attribute__((ext_vector_type(8))) short short8;
typedef __attribute__((ext_vector_type(4))) float f32x4;
typedef __attribute__((ext_vector_type(4))) unsigned short us4;

constexpr int B_ = 2;
constexpr int H_ = 8;
constexpr int KVH_ = 4;
constexpr int S_ = 2048;
constexpr int D_ = 256;
constexpr int HID_ = 2304;
constexpr int QKVN_ = 4096;   // 2048 q + 1024 k + 1024 v
constexpr int AON_ = 2048;    // H_*D_

__device__ __forceinline__ float b2f(u16 u) {
  union { float f; unsigned int i; } x; x.i = ((unsigned int)u) << 16; return x.f;
}
__device__ __forceinline__ u16 f2b(float f) {
  unsigned int x = __float_as_uint(f);
  unsigned int r = (x + 0x7fffu + ((x >> 16) & 1u)) >> 16;
  return (u16)r;
}
// raw v_exp_f32: computes 2^x (no ln2 conversion mul)
__device__ __forceinline__ float exp2_raw(float x) {
  float r;
  asm("v_exp_f32 %0, %1" : "=v"(r) : "v"(x));
  return r;
}
// packed f32x2 -> bf16x2 (RTNE, identical result to f2b pair)
__device__ __forceinline__ unsigned int cvt_pk_bf16(float lo, float hi) {
  unsigned int r;
  asm("v_cvt_pk_bf16_f32 %0, %1, %2" : "=v"(r) : "v"(lo), "v"(hi));
  return r;
}

// ---------------- prep: cast + 4 weight transposes, grid-strided ----
__global__ void prep_kernel(const float* __restrict__ hidden,
                            const float* __restrict__ s0, const float* __restrict__ s1,
                            const float* __restrict__ s2, const float* __restrict__ s3,
                            u16* __restrict__ hsOut,
                            u16* __restrict__ d0, u16* __restrict__ d1,
                            u16* __restrict__ d2, u16* __restrict__ d3) {
  __shared__ float tile[64][65];
  int t = threadIdx.x;
  for (int bx = blockIdx.x; bx < 12672; bx += gridDim.x) {
    if (bx < 9216) {  // cast fp32 -> bf16
      size_t i = ((size_t)bx * 256 + t) * 4;
      float4 v = *(const float4*)(hidden + i);
      unsigned int lo = (unsigned int)f2b(v.x) | ((unsigned int)f2b(v.y) << 16);
      unsigned int hi = (unsigned int)f2b(v.z) | ((unsigned int)f2b(v.w) << 16);
      uint2 o; o.x = lo; o.y = hi;
      *(uint2*)(hsOut + i) = o;
      continue;
    }
    int tt = bx - 9216;
    const float* src; u16* dst; int R, C, cx, cy;
    if (tt < 1152)              { src = s0; dst = d0; R = 2304; C = 2048; cx = tt & 31; cy = tt >> 5; }
    else if ((tt -= 1152) < 576){ src = s1; dst = d1; R = 2304; C = 1024; cx = tt & 15; cy = tt >> 4; }
    else if ((tt -= 576) < 576) { src = s2; dst = d2; R = 2304; C = 1024; cx = tt & 15; cy = tt >> 4; }
    else { tt -= 576;             src = s3; dst = d3; R = 2048; C = 2304; cx = tt % 36; cy = tt / 36; }
    int r0 = cy * 64, c0 = cx * 64;
#pragma unroll
    for (int i = 0; i < 16; ++i) {
      int e = i * 256 + t;
      int r = e >> 6, c = e & 63;
      tile[r][c] = src[(size_t)(r0 + r) * C + (c0 + c)];
    }
    __syncthreads();
#pragma unroll
    for (int i = 0; i < 8; ++i) {
      int e = i * 256 + t;
      int orow = e >> 5;
      int ocol = (e & 31) * 2;
      unsigned int w = (unsigned int)f2b(tile[ocol][orow]) |
                       ((unsigned int)f2b(tile[ocol + 1][orow]) << 16);
      *(unsigned int*)(&dst[(size_t)(c0 + orow) * R + (r0 + ocol)]) = w;
    }
    __syncthreads();  // protect shared tile before next iteration's fill
  }
}

// ---------------- 256x256-tile 8-wave 4-phase/K-tile bf16 GEMM (gemm1) ----
template <int OUTF32>
__global__ __launch_bounds__(512, 2) void gemm_bt8(
    const u16* __restrict__ A, const u16* __restrict__ B, void* __restrict__ Cp,
    int M, int N, int K) {
  __shared__ u16 lds[2][2][2][8192];  // [buf][0=A,1=B][half(128 rows)][16 KiB]
  const int tid = threadIdx.x;
  const int lane = tid & 63;
  const int wave = tid >> 6;
  const int wm = wave >> 2, wn = wave & 3;       // 2 (M) x 4 (N) waves
  const int quad = lane >> 4, l16 = lane & 15;
  const int m0 = blockIdx.y * 256, n0 = blockIdx.x * 256;
  const int nt = K >> 6;  // K-tiles of 64

  const int sub = tid >> 6;
  const int rr = (tid >> 2) & 15;
  const int cc = ((tid & 3) * 8) ^ ((rr & 8) ? 16 : 0);
  const int r_rel = (sub >> 1) * 16 + rr;   // 0..63 row within region
  const int ccol = (sub & 1) * 32 + cc;     // 0..63 k-col (pre-inverse-swizzled)
  const u16* Asrc = A + (size_t)(m0 + r_rel) * K + ccol;
  const u16* Bsrc = B + (size_t)(n0 + r_rel) * K + ccol;
  const int ldsc = tid * 8;  // u16 index of this thread's 16 B chunk in a region

  const int fr_off = l16 * 64 + (((quad * 8) ^ ((l16 & 8) ? 16 : 0)) << 1);

#define GL8(src, dst)                                                                  \
  __builtin_amdgcn_global_load_lds((const __attribute__((address_space(1))) void*)(src), \
                                   (__attribute__((address_space(3))) void*)(dst), 16, 0, 0)
#define STAGE_A(bf, kt, qp) {                                                          \
    const u16* _s = Asrc + (size_t)(kt) * 64;                                          \
    GL8(_s + (size_t)((qp) * 64) * K,       &lds[bf][0][0][(qp) * 4096 + ldsc]);       \
    GL8(_s + (size_t)(128 + (qp) * 64) * K, &lds[bf][0][1][(qp) * 4096 + ldsc]); }
#define STAGE_B(bf, kt, hf) {                                                          \
    const u16* _s = Bsrc + (size_t)(kt) * 64;                                          \
    GL8(_s + (size_t)((hf) * 128) * K,      &lds[bf][1][hf][ldsc]);                    \
    GL8(_s + (size_t)((hf) * 128 + 64) * K, &lds[bf][1][hf][4096 + ldsc]); }
#define LDA(bf, mi, kk) \
  (*(const short8*)((const char*)&lds[bf][0][wm][0] + (mi) * 2048 + (kk) * 1024 + fr_off))
#define LDB(bf, ni, kk) \
  (*(const short8*)((const char*)&lds[bf][1][wn >> 1][0] + ((wn & 1) * 4 + (ni)) * 2048 + (kk) * 1024 + fr_off))

  f32x4 acc[8][4] = {};
  short8 bfr[4][2], af[2][2];

  STAGE_B(0, 0, 0); STAGE_B(0, 0, 1); STAGE_A(0, 0, 0); STAGE_A(0, 0, 1);
  STAGE_B(1, 1, 0); STAGE_B(1, 1, 1); STAGE_A(1, 1, 0);
  asm volatile("s_waitcnt vmcnt(6)" ::: "memory");
  __builtin_amdgcn_s_barrier();

#define PHASE(q, STG, VMW)                                                             \
    _Pragma("unroll") for (int i = 0; i < 2; ++i)                                      \
      _Pragma("unroll") for (int kk = 0; kk < 2; ++kk) af[i][kk] = LDA(c, 2 * (q) + i, kk); \
    STG; VMW;                                                                          \
    __builtin_amdgcn_s_barrier();                                                      \
    asm volatile("s_waitcnt lgkmcnt(0)" ::: "memory");                                 \
    __builtin_amdgcn_sched_barrier(0);                                                 \
    __builtin_amdgcn_s_setprio(1);                                                     \
    _Pragma("unroll") for (int i = 0; i < 2; ++i)                                      \
      _Pragma("unroll") for (int ni = 0; ni < 4; ++ni)                                 \
        _Pragma("unroll") for (int kk = 0; kk < 2; ++kk)                               \
          acc[2 * (q) + i][ni] = __builtin_amdgcn_mfma_f32_16x16x32_bf16(              \
              af[i][kk], bfr[ni][kk], acc[2 * (q) + i][ni], 0, 0, 0);                  \
    __builtin_amdgcn_s_setprio(0);                                                     \
    __builtin_amdgcn_s_barrier();

  for (int T = 0; T < nt; ++T) {
    const int c = T & 1;
#pragma unroll
    for (int ni = 0; ni < 4; ++ni)
#pragma unroll
      for (int kk = 0; kk < 2; ++kk) bfr[ni][kk] = LDB(c, ni, kk);
    PHASE(0, if (T + 1 < nt) STAGE_A(c ^ 1, T + 1, 1), )
    PHASE(1, if (T + 2 < nt) STAGE_B(c, T + 2, 0), )
    PHASE(2, if (T + 2 < nt) STAGE_B(c, T + 2, 1), )
    PHASE(3, if (T + 2 < nt) STAGE_A(c, T + 2, 0),
          if (T + 2 >= nt) { asm volatile("s_waitcnt vmcnt(0)" ::: "memory"); }
          else             { asm volatile("s_waitcnt vmcnt(6)" ::: "memory"); })
  }
#undef PHASE
#undef LDA
#undef LDB
#undef STAGE_A
#undef STAGE_B
#undef GL8

#pragma unroll
  for (int mi = 0; mi < 8; ++mi) {
#pragma unroll
    for (int ni = 0; ni < 4; ++ni) {
#pragma unroll
      for (int r = 0; r < 4; ++r) {
        int row = m0 + wm * 128 + mi * 16 + quad * 4 + r;
        int col = n0 + wn * 64 + ni * 16 + l16;
        if (OUTF32)
          ((float*)Cp)[(size_t)row * N + col] = acc[mi][ni][r];
        else
          ((u16*)Cp)[(size_t)row * N + col] = f2b(acc[mi][ni][r]);
      }
    }
  }
}

// ---------------- m97-style 128x128 bf16 GEMM (gemm2) ----
template <int OUTF32>
__global__ __launch_bounds__(256, 2) void gemm_bt(
    const u16* __restrict__ A, const u16* __restrict__ B, void* __restrict__ Cp,
    int M, int N, int K) {
  __shared__ u16 As[128 * 32];
  __shared__ u16 Bs[128 * 32];
  int m0 = blockIdx.y * 128, n0 = blockIdx.x * 128;
  int tid = threadIdx.x;
  int lane = tid & 63, wave = tid >> 6;
  int wy = wave >> 1, wx = wave & 1;
  int quad = lane >> 4, l16 = lane & 15;
  f32x4 acc[4][4] = {};
  for (int k0 = 0; k0 < K; k0 += 32) {
#pragma unroll
    for (int i = 0; i < 2; ++i) {
      int chunk = i * 256 + tid;
      int row = chunk >> 2, col = (chunk & 3) << 3;
      __builtin_amdgcn_global_load_lds(
          (const __attribute__((address_space(1))) void*)(A + (size_t)(m0 + row) * K + k0 + col),
          (__attribute__((address_space(3))) void*)(As + chunk * 8), 16, 0, 0);
    }
#pragma unroll
    for (int i = 0; i < 2; ++i) {
      int chunk = i * 256 + tid;
      int row = chunk >> 2, col = (chunk & 3) << 3;
      __builtin_amdgcn_global_load_lds(
          (const __attribute__((address_space(1))) void*)(B + (size_t)(n0 + row) * K + k0 + col),
          (__attribute__((address_space(3))) void*)(Bs + chunk * 8), 16, 0, 0);
    }
    __syncthreads();
    short8 af[4], bf[4];
#pragma unroll
    for (int mi = 0; mi < 4; ++mi)
      af[mi] = *(const short8*)(As + (wy * 64 + mi * 16 + l16) * 32 + quad * 8);
#pragma unroll
    for (int ni = 0; ni < 4; ++ni)
      bf[ni] = *(const short8*)(Bs + (wx * 64 + ni * 16 + l16) * 32 + quad * 8);
#pragma unroll
    for (int mi = 0; mi < 4; ++mi)
#pragma unroll
      for (int ni = 0; ni < 4; ++ni)
        acc[mi][ni] = __builtin_amdgcn_mfma_f32_16x16x32_bf16(af[mi], bf[ni], acc[mi][ni], 0, 0, 0);
    __syncthreads();
  }
#pragma unroll
  for (int mi = 0; mi < 4; ++mi) {
#pragma unroll
    for (int ni = 0; ni < 4; ++ni) {
#pragma unroll
      for (int r = 0; r < 4; ++r) {
        int row = m0 + wy * 64 + mi * 16 + quad * 4 + r;
        int col = n0 + wx * 64 + ni * 16 + l16;
        if (OUTF32)
          ((float*)Cp)[(size_t)row * N + col] = acc[mi][ni][r];
        else
          ((u16*)Cp)[(size_t)row * N + col] = f2b(acc[mi][ni][r]);
      }
    }
  }
}

// ---------------- rope_tv: RoPE (blocks 0..511) + V transpose (512..1535) -----
__global__ void rope_tv_kernel(const u16* __restrict__ qkv, const float* __restrict__ cs,
                               const float* __restrict__ sn, u16* __restrict__ Qr,
                               u16* __restrict__ Kr, u16* __restrict__ Vt) {
  __shared__ u16 tile[64][72];
  int bx = blockIdx.x;
  int t = threadIdx.x;
  if (bx < 512) {  // RoPE v2: paired halves, ushort4 vectorized
    int row = bx * 8 + (t >> 5);
    int d0 = (t & 31) * 4;
    int b = row >> 11, s = row & 2047;
    const u16* qrow = qkv + (size_t)row * QKVN_;
    float4 c4 = *(const float4*)(cs + (size_t)row * D_ + d0);
    float4 s4 = *(const float4*)(sn + (size_t)row * D_ + d0);
    float c[4] = {c4.x, c4.y, c4.z, c4.w};
    float sv[4] = {s4.x, s4.y, s4.z, s4.w};
#pragma unroll
    for (int h = 0; h < H_ + KVH_; ++h) {
      const u16* src = qrow + (h < H_ ? h * D_ : 2048 + (h - H_) * D_);
      us4 lo = *(const us4*)(src + d0);
      us4 hi = *(const us4*)(src + 128 + d0);
      us4 olo, ohi;
#pragma unroll
      for (int j = 0; j < 4; ++j) {
        float xl = b2f(lo[j]), xh = b2f(hi[j]);
        olo[j] = f2b(xl * c[j] - xh * sv[j]);
        ohi[j] = f2b(xh * c[j] + xl * sv[j]);
      }
      u16* dst = (h < H_)
          ? Qr + ((size_t)(b * H_ + h) * S_ + s) * D_
          : Kr + ((size_t)(b * KVH_ + (h - H_)) * S_ + s) * D_;
      *(us4*)(dst + d0) = olo;
      *(us4*)(dst + 128 + d0) = ohi;
    }
    return;
  }
  // V transpose
  int tt = bx - 512;
  int g = tt >> 7;             // b*KVH+kvh
  int rem = tt & 127;
  int s0 = (rem >> 2) * 64;
  int d0 = (rem & 3) * 64;
  int b = g >> 2, kvh = g & 3;
#pragma unroll
  for (int i = 0; i < 8; ++i) {
    int e = i * 256 + t;
    int r = e >> 5, c = (e & 31) * 2;
    unsigned int v = *(const unsigned int*)(&qkv[(size_t)(b * S_ + s0 + r) * QKVN_ +
                                                 3072 + kvh * D_ + d0 + c]);
    tile[r][c] = (u16)v;
    tile[r][c + 1] = (u16)(v >> 16);
  }
  __syncthreads();
#pragma unroll
  for (int i = 0; i < 8; ++i) {
    int e = i * 256 + t;
    int orow = e >> 5, ocol = (e & 31) * 2;
    unsigned int w = (unsigned int)tile[ocol][orow] |
                     ((unsigned int)tile[ocol + 1][orow] << 16);
    *(unsigned int*)(&Vt[((size_t)g * D_ + d0 + orow) * S_ + s0 + ocol]) = w;
  }
}

// ---------------- flash attention v8e: v8c with bf16 split-K partials ----------
// Identical structure to v8c (proven 78.3-79.4us). Only change: Op partials are
// stored as bf16 (f2b RTNE) instead of fp32 -- halves attn's epilogue store
// bytes and combine's partial-read traffic (67MB saved). Lp stays fp32.
__global__ __launch_bounds__(256, 2) void attn_kernel(
    const u16* __restrict__ Qr, const u16* __restrict__ Kr, const u16* __restrict__ Vt,
    u16* __restrict__ Op0, u16* __restrict__ Op1,
    float* __restrict__ Lp0, float* __restrict__ Lp1) {
  __shared__ u16 Ks[2][32 * 256]; // 2x16 KB, chunk-swizzled (^ sw(row))
  __shared__ u16 Vs[2][32 * 256]; // 2x16 KB, chunk-swizzled (^ (d>>1)&3)
  int bx = blockIdx.x;
  int h = bx & 7;                 // XCD pin: round-robin dispatch -> XCD = bx%8
  int u = bx >> 4;
  int sp = (bx >> 3) & 1;
  int kvh = h >> 1;  // N_REP = 2
  int tid = threadIdx.x, wave = tid >> 6, lane = tid & 63;
  int quad = lane >> 4, l16 = lane & 15;
  u16* Op = sp ? Op1 : Op0;
  float* Lp = sp ? Lp1 : Lp0;
  int ksrc_s[4], ksrc_c[4], vsrc_d[4], vsrc_s[4];
#pragma unroll
  for (int i = 0; i < 4; ++i) {
    int p = i * 256 + tid;
    int sK = p >> 5;
    ksrc_s[i] = sK;
    ksrc_c[i] = (p & 31) ^ ((sK & 3) | (((sK >> 3) & 1) << 2));
    vsrc_d[i] = p >> 2;
    vsrc_s[i] = (p & 3) ^ ((p >> 3) & 3);
  }
  // K-fragment read geometry (swapped-QK, permuted rows):
  const int kg = l16 >> 2, ka = l16 & 3;
  const int srow0 = 8 * kg + ka;           // n=0; n=1 adds 4
  const int ksw = ka | ((kg & 1) << 2);    // sw(srow), same for n=0,1

  for (int part = 0; part < 2; ++part) {
    int b = part;
    int qt = (part == 0) ? u : (31 - u);
    int q0 = qt * 64;
    int beg = sp ? (qt + 1) : 0;
    int end = sp ? (2 * qt + 2) : (qt + 1);
    const u16* Qbase = Qr + ((size_t)(b * H_ + h) * S_ + q0 + wave * 16 + l16) * D_;
    short8 qf[8];
#pragma unroll
    for (int kk = 0; kk < 8; ++kk)
      qf[kk] = *(const short8*)(Qbase + kk * 32 + quad * 8);
    const u16* Kbase = Kr + (size_t)(b * KVH_ + kvh) * S_ * D_;
    const u16* Vbase = Vt + (size_t)(b * KVH_ + kvh) * D_ * S_;
    float lp = 0.f;
    f32x4 o_acc[16] = {};
    const int qq = q0 + wave * 16 + l16;

#define STAGE(KT, BUF)                                                                   \
    {                                                                                    \
      int k0s = (KT) * 32;                                                               \
      _Pragma("unroll") for (int i = 0; i < 4; ++i) {                                    \
        int p = i * 256 + tid;                                                           \
        __builtin_amdgcn_global_load_lds(                                                \
            (const __attribute__((address_space(1))) void*)(Kbase +                      \
                (size_t)(k0s + ksrc_s[i]) * D_ + ksrc_c[i] * 8),                         \
            (__attribute__((address_space(3))) void*)(&Ks[BUF][0] + p * 8), 16, 0, 0);   \
      }                                                                                  \
      _Pragma("unroll") for (int i = 0; i < 4; ++i) {                                    \
        int p = i * 256 + tid;                                                           \
        __builtin_amdgcn_global_load_lds(                                                \
            (const __attribute__((address_space(1))) void*)(Vbase +                      \
                (size_t)vsrc_d[i] * S_ + k0s + vsrc_s[i] * 8),                           \
            (__attribute__((address_space(3))) void*)(&Vs[BUF][0] + p * 8), 16, 0, 0);   \
      }                                                                                  \
    }

    STAGE(beg, 0);
    __syncthreads();
    for (int kt = beg; kt < end; ++kt) {
      int k0 = kt * 32;
      int cur = (kt - beg) & 1;
      if (kt + 1 < end) STAGE(kt + 1, cur ^ 1);
      // S^T = K Q^T (A = permuted K-tile, B = Q)
      f32x4 sacc[2] = {};
      __builtin_amdgcn_s_setprio(1);
#pragma unroll
      for (int n = 0; n < 2; ++n) {
        const u16* kb = &Ks[cur][0] + (srow0 + 4 * n) * 256;
#pragma unroll
        for (int kk = 0; kk < 8; ++kk) {
          int phys = (kk * 4 + quad) ^ ksw;
          short8 kfr = *(const short8*)(kb + phys * 8);
          sacc[n] = __builtin_amdgcn_mfma_f32_16x16x32_bf16(kfr, qf[kk], sacc[n], 0, 0, 0);
        }
      }
      __builtin_amdgcn_s_setprio(0);
      // fused softcap+softmax via exp2: E = 2^(s*0.0025*log2e), ee = 2^(-100*log2e*rcp(E+1))
      bool full = (k0 + 31 <= q0 + wave * 16);  // wave-uniform
#pragma unroll
      for (int n = 0; n < 2; ++n) {
#pragma unroll
        for (int r = 0; r < 4; ++r) {
          float E = exp2_raw(sacc[n][r] * 0.0036067376f);
          float ee = exp2_raw(__frcp_rn(E + 1.0f) * -144.2695041f);
          if (!full) {
            int key = k0 + 8 * quad + 4 * n + r;   // lane holds keys 8*quad + 4n + r
            ee = (key <= qq) ? ee : 0.0f;
          }
          lp += ee;
          sacc[n][r] = ee;
        }
      }
      // pack P in-register: frag elem j = key 8*quad+j, j = 4n+r
      union { short8 s8; unsigned int d[4]; } pu;
      pu.d[0] = cvt_pk_bf16(sacc[0][0], sacc[0][1]);
      pu.d[1] = cvt_pk_bf16(sacc[0][2], sacc[0][3]);
      pu.d[2] = cvt_pk_bf16(sacc[1][0], sacc[1][1]);
      pu.d[3] = cvt_pk_bf16(sacc[1][2], sacc[1][3]);
      short8 pa = pu.s8;
      // O += P V  (pa is PV's A-fragment directly; no LDS round-trip)
      __builtin_amdgcn_s_setprio(1);
#pragma unroll
      for (int dt = 0; dt < 16; ++dt) {
        int d = dt * 16 + l16;
        int phys = quad ^ ((d >> 1) & 3);
        short8 vb = *(const short8*)(&Vs[cur][0] + d * 32 + phys * 8);
        o_acc[dt] = __builtin_amdgcn_mfma_f32_16x16x32_bf16(pa, vb, o_acc[dt], 0, 0, 0);
      }
      __builtin_amdgcn_s_setprio(0);
      __syncthreads();  // buffer handoff (prefetch long since landed)
    }
#undef STAGE
    // denominator partial: lane holds sum for q=l16 over its 8 keys/iter; reduce quads
    lp += __shfl_xor(lp, 16, 64);
    lp += __shfl_xor(lp, 32, 64);
    if (lane < 16)
      Lp[((size_t)(b * H_ + h)) * S_ + q0 + wave * 16 + lane] = lp;
    // unnormalized bf16 partial O (row q = quad*4+r, col d = dt*16+l16)
#pragma unroll
    for (int dt = 0; dt < 16; ++dt)
#pragma unroll
      for (int r = 0; r < 4; ++r) {
        int row = b * S_ + q0 + wave * 16 + quad * 4 + r;
        int col = h * D_ + dt * 16 + l16;
        Op[(size_t)row * AON_ + col] = f2b(o_acc[dt][r]);
      }
  }
}

// ---------------- combine splits: Ao = (O0+O1)/(l0+l1), bf16-in bf16-out ------
__global__ void combine_kernel(const u16* __restrict__ Op0, const u16* __restrict__ Op1,
                               const float* __restrict__ Lp0, const float* __restrict__ Lp1,
                               u16* __restrict__ Ao) {
  for (size_t idx = (size_t)blockIdx.x * 256 + threadIdx.x; idx < (size_t)2097152;
       idx += (size_t)gridDim.x * 256) {
    size_t row = idx >> 9;
    int c4 = ((int)idx & 511) * 4;
    us4 a = *(const us4*)(Op0 + row * AON_ + c4);
    us4 b4v = *(const us4*)(Op1 + row * AON_ + c4);
    int b = (int)(row >> 11), s = (int)row & 2047;
    int h = c4 >> 8;
    size_t li = ((size_t)(b * H_ + h)) * S_ + s;
    float inv = 1.0f / (Lp0[li] + Lp1[li]);
    unsigned int lo = (unsigned int)f2b((b2f(a[0]) + b2f(b4v[0])) * inv) |
                      ((unsigned int)f2b((b2f(a[1]) + b2f(b4v[1])) * inv) << 16);
    unsigned int hi = (unsigned int)f2b((b2f(a[2]) + b2f(b4v[2])) * inv) |
                      ((unsigned int)f2b((b2f(a[3]) + b2f(b4v[3])) * inv) << 16);
    uint2 o; o.x = lo; o.y = hi;
    *(uint2*)(Ao + row * AON_ + c4) = o;
  }
}

extern "C" void kernel_launch(void* const* d_in, const int* in_sizes, int n_in,
                              void* d_out, int out_size, void* d_ws, size_t ws_size,
                              hipStream_t stream) {
  const float* hidden = (const float*)d_in[0];
  const float* cosp = (const float*)d_in[1];
  const float* sinp = (const float*)d_in[2];
  const float* Wq = (const float*)d_in[4];
  const float* Wk = (const float*)d_in[5];
  const float* Wv = (const float*)d_in[6];
  const float* Wo = (const float*)d_in[7];

  u16* hs  = (u16*)d_ws;                              // 4096 x 2304 (dead after gemm1)
  u16* WT  = hs  + (size_t)4096 * HID_;               // 4096 x 2304 (dead after gemm1)
  u16* WoT = WT  + (size_t)4096 * HID_;               // 2304 x 2048 (live till gemm2)
  u16* qkv = WoT + (size_t)HID_ * AON_;               // 4096 x 4096 (dead after rope_tv)
  u16* Qr  = qkv + (size_t)4096 * QKVN_;              // B,H,S,D
  u16* Kr  = Qr  + (size_t)B_ * H_ * S_ * D_;         // B,KVH,S,D
  u16* Vt  = Kr  + (size_t)B_ * KVH_ * S_ * D_;       // B,KVH,D,S
  u16* Ao  = Vt  + (size_t)B_ * KVH_ * S_ * D_;       // 4096 x 2048
  float* Lp0 = (float*)(Ao + (size_t)4096 * AON_);    // 2*8*2048 fp32
  float* Lp1 = Lp0 + (size_t)B_ * H_ * S_;            // 2*8*2048 fp32
  u16* Op0 = hs;     // hs+WT region (bf16 partial: 16.8 MB, fits 18.9 MB)
  u16* Op1 = qkv;    // qkv region (bf16 partial: 16.8 MB, fits 33.5 MB)

  prep_kernel<<<2112, 256, 0, stream>>>(
      hidden, Wq, Wk, Wv, Wo, hs,
      WT, WT + (size_t)2048 * HID_, WT + (size_t)3072 * HID_, WoT);
  gemm_bt8<0><<<dim3(16, 16), 512, 0, stream>>>(hs, WT, qkv, 4096, QKVN_, HID_);
  rope_tv_kernel<<<1536, 256, 0, stream>>>(qkv, cosp, sinp, Qr, Kr, Vt);
  attn_kernel<<<dim3(512), 256, 0, stream>>>(Qr, Kr, Vt, Op0, Op1, Lp0, Lp1);
  combine_kernel<<<2048, 256, 0, stream>>>(Op0, Op1, Lp0, Lp1, Ao);
  gemm_bt<1><<<dim3(18, 32), 256, 0, stream>>>(Ao, WoT, d_out, 4096, HID_, 2048);
}